// Round 2
// baseline (25.636 us; speedup 1.0000x reference)
//
#include <hip/hip_runtime.h>

// Entropic water-filling:  w_i = min(c, e_i * u),  e_i = exp(x_i),
//   u solved by monotone active-set fixed point:
//   u_0 = 1/S,  A_t = { e_i >= c/u_t },  u_{t+1} = (1 - c|A_t|) / (S - sum_{A_t} e_i).
// One wave per TWO rows (r and r+half) for ILP on the shuffle chains.
// |A_t| comes from __ballot + popc (scalar pipe, uniform for free); the
// s_act butterfly (6 ds-ops) runs only on iterations where the set changed.

#define N_ASSETS 512
#define C_CAP 0.02f

__device__ __forceinline__ float wave_sum(float v) {
#pragma unroll
  for (int m = 1; m < 64; m <<= 1) v += __shfl_xor(v, m, 64);
  return v;
}

__global__ __launch_bounds__(256) void waterfill_kernel(
    const float* __restrict__ x, float* __restrict__ out, int half) {
  const int wave = threadIdx.x >> 6;
  const int lane = threadIdx.x & 63;
  const int r0 = blockIdx.x * 4 + wave;
  if (r0 >= half) return;
  const size_t off0 = (size_t)r0 * N_ASSETS;
  const size_t off1 = (size_t)(r0 + half) * N_ASSETS;

  const float4* xa = reinterpret_cast<const float4*>(x + off0);
  const float4* xb = reinterpret_cast<const float4*>(x + off1);
  float4 A0 = xa[lane], A1 = xa[lane + 64];
  float4 B0 = xb[lane], B1 = xb[lane + 64];

  float ea[8], eb[8];
  ea[0] = __expf(A0.x); ea[1] = __expf(A0.y); ea[2] = __expf(A0.z); ea[3] = __expf(A0.w);
  ea[4] = __expf(A1.x); ea[5] = __expf(A1.y); ea[6] = __expf(A1.z); ea[7] = __expf(A1.w);
  eb[0] = __expf(B0.x); eb[1] = __expf(B0.y); eb[2] = __expf(B0.z); eb[3] = __expf(B0.w);
  eb[4] = __expf(B1.x); eb[5] = __expf(B1.y); eb[6] = __expf(B1.z); eb[7] = __expf(B1.w);

  float sa = ((ea[0] + ea[1]) + (ea[2] + ea[3])) + ((ea[4] + ea[5]) + (ea[6] + ea[7]));
  float sb = ((eb[0] + eb[1]) + (eb[2] + eb[3])) + ((eb[4] + eb[5]) + (eb[6] + eb[7]));
  // Interleaved butterflies: two independent 6-deep chains overlap.
#pragma unroll
  for (int m = 1; m < 64; m <<= 1) {
    sa += __shfl_xor(sa, m, 64);
    sb += __shfl_xor(sb, m, 64);
  }

  float ua = 1.0f / sa, ub = 1.0f / sb;
  int ka_prev = 0, kb_prev = 0;     // u = 1/S is exact for the empty active set
  bool done_a = false, done_b = false;
  for (int it = 0; it < 16 && !(done_a && done_b); ++it) {
    if (!done_a) {
      const float th = C_CAP / ua;  // e >= th  <=>  e*u >= c
      int k = 0;
#pragma unroll
      for (int j = 0; j < 8; ++j) k += (int)__popcll(__ballot(ea[j] >= th));
      if (k == ka_prev) {
        done_a = true;              // set unchanged -> u already exact for it
      } else {
        float s = 0.0f;
#pragma unroll
        for (int j = 0; j < 8; ++j) s += (ea[j] >= th) ? ea[j] : 0.0f;
        s = wave_sum(s);
        ua = fmaxf(1.0f - C_CAP * (float)k, 1e-12f) / fmaxf(sa - s, 1e-30f);
        ka_prev = k;
      }
    }
    if (!done_b) {
      const float th = C_CAP / ub;
      int k = 0;
#pragma unroll
      for (int j = 0; j < 8; ++j) k += (int)__popcll(__ballot(eb[j] >= th));
      if (k == kb_prev) {
        done_b = true;
      } else {
        float s = 0.0f;
#pragma unroll
        for (int j = 0; j < 8; ++j) s += (eb[j] >= th) ? eb[j] : 0.0f;
        s = wave_sum(s);
        ub = fmaxf(1.0f - C_CAP * (float)k, 1e-12f) / fmaxf(sb - s, 1e-30f);
        kb_prev = k;
      }
    }
  }

  float* wa = out + off0;
  float* wb = out + off1;
  float4 oa0, oa1, ob0, ob1;
  oa0.x = fminf(C_CAP, ea[0] * ua); oa0.y = fminf(C_CAP, ea[1] * ua);
  oa0.z = fminf(C_CAP, ea[2] * ua); oa0.w = fminf(C_CAP, ea[3] * ua);
  oa1.x = fminf(C_CAP, ea[4] * ua); oa1.y = fminf(C_CAP, ea[5] * ua);
  oa1.z = fminf(C_CAP, ea[6] * ua); oa1.w = fminf(C_CAP, ea[7] * ua);
  ob0.x = fminf(C_CAP, eb[0] * ub); ob0.y = fminf(C_CAP, eb[1] * ub);
  ob0.z = fminf(C_CAP, eb[2] * ub); ob0.w = fminf(C_CAP, eb[3] * ub);
  ob1.x = fminf(C_CAP, eb[4] * ub); ob1.y = fminf(C_CAP, eb[5] * ub);
  ob1.z = fminf(C_CAP, eb[6] * ub); ob1.w = fminf(C_CAP, eb[7] * ub);
  reinterpret_cast<float4*>(wa)[lane] = oa0;
  reinterpret_cast<float4*>(wa)[lane + 64] = oa1;
  reinterpret_cast<float4*>(wb)[lane] = ob0;
  reinterpret_cast<float4*>(wb)[lane + 64] = ob1;
}

extern "C" void kernel_launch(void* const* d_in, const int* in_sizes, int n_in,
                              void* d_out, int out_size, void* d_ws, size_t ws_size,
                              hipStream_t stream) {
  const float* x = (const float*)d_in[0];
  float* out = (float*)d_out;
  const int n_rows = in_sizes[0] / N_ASSETS;
  const int half = n_rows >> 1;
  const int grid = (half + 3) / 4;  // 4 waves/block, 2 rows/wave
  waterfill_kernel<<<grid, 256, 0, stream>>>(x, out, half);
}

// Round 4
// 25.445 us; speedup vs baseline: 1.0075x; 1.0075x over previous
//
#include <hip/hip_runtime.h>

// Entropic water-filling:  w_i = min(c, e_i * u),  e_i = exp(x_i),
//   u by monotone active-set fixed point:
//   u_0 = 1/S,  A_t = { e_i >= c/u_t },  u_{t+1} = (1 - c|A_t|) / (S - sum_{A_t} e_i).
// One wave per row, 8 elems/lane as two 16B loads. Touch-once streaming:
// nontemporal loads/stores so L2/L3 don't retain dead lines.
// NOTE: __builtin_nontemporal_* needs a NATIVE vector type (ext_vector_type),
// not HIP's float4 struct.

#define N_ASSETS 512
#define C_CAP 0.02f
#define ROWS_PER_BLOCK 4

typedef float fx4 __attribute__((ext_vector_type(4)));

__global__ __launch_bounds__(256) void waterfill_kernel(
    const float* __restrict__ x, float* __restrict__ out, int n_rows) {
  const int wave = threadIdx.x >> 6;
  const int lane = threadIdx.x & 63;
  const int row = blockIdx.x * ROWS_PER_BLOCK + wave;
  if (row >= n_rows) return;

  const fx4* xr = reinterpret_cast<const fx4*>(x + (size_t)row * N_ASSETS);
  fx4* wr = reinterpret_cast<fx4*>(out + (size_t)row * N_ASSETS);

  const fx4 a = __builtin_nontemporal_load(xr + lane);
  const fx4 b = __builtin_nontemporal_load(xr + lane + 64);

  float e[8];
  e[0] = __expf(a.x); e[1] = __expf(a.y); e[2] = __expf(a.z); e[3] = __expf(a.w);
  e[4] = __expf(b.x); e[5] = __expf(b.y); e[6] = __expf(b.z); e[7] = __expf(b.w);

  float S = ((e[0] + e[1]) + (e[2] + e[3])) + ((e[4] + e[5]) + (e[6] + e[7]));
#pragma unroll
  for (int m = 1; m < 64; m <<= 1) S += __shfl_xor(S, m, 64);

  float u = 1.0f / S;  // exact for empty active set
  int kprev = 0;
  for (int it = 0; it < 16; ++it) {
    const float th = C_CAP / u;  // e >= th  <=>  e*u >= c
    int k = 0;
#pragma unroll
    for (int j = 0; j < 8; ++j) k += (int)__popcll(__ballot(e[j] >= th));
    if (k == kprev) break;       // set unchanged -> u already exact for it
    float s = 0.0f;
#pragma unroll
    for (int j = 0; j < 8; ++j) s += (e[j] >= th) ? e[j] : 0.0f;
#pragma unroll
    for (int m = 1; m < 64; m <<= 1) s += __shfl_xor(s, m, 64);
    u = fmaxf(1.0f - C_CAP * (float)k, 1e-12f) / fmaxf(S - s, 1e-30f);
    kprev = k;
  }

  fx4 oa, ob;
  oa.x = fminf(C_CAP, e[0] * u); oa.y = fminf(C_CAP, e[1] * u);
  oa.z = fminf(C_CAP, e[2] * u); oa.w = fminf(C_CAP, e[3] * u);
  ob.x = fminf(C_CAP, e[4] * u); ob.y = fminf(C_CAP, e[5] * u);
  ob.z = fminf(C_CAP, e[6] * u); ob.w = fminf(C_CAP, e[7] * u);
  __builtin_nontemporal_store(oa, wr + lane);
  __builtin_nontemporal_store(ob, wr + lane + 64);
}

extern "C" void kernel_launch(void* const* d_in, const int* in_sizes, int n_in,
                              void* d_out, int out_size, void* d_ws, size_t ws_size,
                              hipStream_t stream) {
  const float* x = (const float*)d_in[0];
  float* out = (float*)d_out;
  const int n_rows = in_sizes[0] / N_ASSETS;
  const int grid = (n_rows + ROWS_PER_BLOCK - 1) / ROWS_PER_BLOCK;
  waterfill_kernel<<<grid, 256, 0, stream>>>(x, out, n_rows);
}